// Round 2
// baseline (2994.059 us; speedup 1.0000x reference)
//
#include <hip/hip_runtime.h>
#include <hip/hip_bf16.h>
#include <math.h>

#define HIDC 128
#define NH 8
#define HD 16
#define NCLS 4

// ---- storage helpers (float or bf16 backing for k/q/v) ----
__device__ __forceinline__ float ldv(const float* p) { return *p; }
__device__ __forceinline__ float ldv(const __hip_bfloat16* p) { return __bfloat162float(*p); }
__device__ __forceinline__ void stv(float* p, float v) { *p = v; }
__device__ __forceinline__ void stv(__hip_bfloat16* p, float v) { *p = __float2bfloat16(v); }

// ---- ordered-float encoding for atomicMax on unsigned ----
__device__ __forceinline__ unsigned enc_f(float f) {
    unsigned b = __float_as_uint(f);
    return (b & 0x80000000u) ? ~b : (b | 0x80000000u);
}
__device__ __forceinline__ float dec_f(unsigned u) {
    unsigned b = (u & 0x80000000u) ? (u & 0x7fffffffu) : ~u;
    return __uint_as_float(b);
}

__global__ void zero_u32(unsigned* __restrict__ p, long n)
{
    long i = (long)blockIdx.x * blockDim.x + threadIdx.x;
    long stride = (long)gridDim.x * blockDim.x;
    for (; i < n; i += stride) p[i] = 0u;
}

// C[row, 0..127] = relu(A[row]·W + b); A: N x K (K<=128), W: K x 128 row-major
__global__ void rowgemm_relu(const float* __restrict__ A, const float* __restrict__ W,
                             const float* __restrict__ b, float* __restrict__ C, int K)
{
    __shared__ float ash[HIDC];
    int row = blockIdx.x;
    int t = threadIdx.x;
    for (int i = t; i < K; i += HIDC) ash[i] = A[(long)row * K + i];
    __syncthreads();
    float acc = b[t];
    for (int k = 0; k < K; ++k) acc = fmaf(ash[k], W[k * HIDC + t], acc);
    C[(long)row * HIDC + t] = acc > 0.f ? acc : 0.f;
}

// fused K/Q/V projections: X (N x 128) -> K,Q,V (N x 128 each, storage type T)
template <typename T>
__global__ void kqv_kernel(const float* __restrict__ X,
                           const float* __restrict__ Wk, const float* __restrict__ bk,
                           const float* __restrict__ Wq, const float* __restrict__ bq,
                           const float* __restrict__ Wv, const float* __restrict__ bv,
                           T* __restrict__ Kout, T* __restrict__ Qout, T* __restrict__ Vout)
{
    __shared__ float xs[HIDC];
    int row = blockIdx.x, t = threadIdx.x;
    xs[t] = X[(long)row * HIDC + t];
    __syncthreads();
    float ak = bk[t], aq = bq[t], av = bv[t];
    for (int k = 0; k < HIDC; ++k) {
        float xv = xs[k];
        ak = fmaf(xv, Wk[k * HIDC + t], ak);
        aq = fmaf(xv, Wq[k * HIDC + t], aq);
        av = fmaf(xv, Wv[k * HIDC + t], av);
    }
    long o = (long)row * HIDC + t;
    stv(Kout + o, ak); stv(Qout + o, aq); stv(Vout + o, av);
}

// per-edge logits: a[e,h] = (q[dst,h,:]·(k[src,h,:]@arel[h])) * prel[h] * scale
template <typename T>
__global__ void logits_kernel(const T* __restrict__ Ksrc, const T* __restrict__ Qdst,
                              const int* __restrict__ src, const int* __restrict__ dst,
                              const float* __restrict__ arel, const float* __restrict__ prel,
                              float* __restrict__ aout, unsigned* __restrict__ amax,
                              float scale)
{
    __shared__ float ksh[HIDC];
    int e = blockIdx.x;
    int t = threadIdx.x;
    int h = t >> 4, f = t & 15;
    int s = src[e], dn = dst[e];
    ksh[t] = ldv(Ksrc + (long)s * HIDC + t);
    __syncthreads();
    float ke = 0.f;
    const float* ar = arel + h * HD * HD + f;
    const float* kk = ksh + h * HD;
    #pragma unroll
    for (int dd = 0; dd < HD; ++dd) ke = fmaf(kk[dd], ar[dd * HD], ke);
    float part = ldv(Qdst + (long)dn * HIDC + t) * ke;
    #pragma unroll
    for (int off = 8; off; off >>= 1) part += __shfl_xor(part, off, 16);
    if (f == 0) {
        float a = part * prel[h] * scale;
        aout[(long)e * NH + h] = a;
        atomicMax(&amax[(long)dn * NH + h], enc_f(a));
    }
}

// per-edge aggregation: ae = exp(a - amax[dst]); den += ae; msg += ae * (v[src]@mrel)
template <typename T>
__global__ void agg_kernel(const T* __restrict__ Vsrc,
                           const int* __restrict__ src, const int* __restrict__ dst,
                           const float* __restrict__ mrel,
                           const float* __restrict__ ain, const unsigned* __restrict__ amax,
                           float* __restrict__ den, float* __restrict__ msg)
{
    __shared__ float vsh[HIDC];
    int e = blockIdx.x;
    int t = threadIdx.x;
    int h = t >> 4, f = t & 15;
    int s = src[e], dn = dst[e];
    vsh[t] = ldv(Vsrc + (long)s * HIDC + t);
    __syncthreads();
    float ve = 0.f;
    const float* mr = mrel + h * HD * HD + f;
    const float* vv = vsh + h * HD;
    #pragma unroll
    for (int dd = 0; dd < HD; ++dd) ve = fmaf(vv[dd], mr[dd * HD], ve);
    float a = ain[(long)e * NH + h];
    float m = dec_f(amax[(long)dn * NH + h]);
    float ae = __expf(a - m);
    atomicAdd(&msg[(long)dn * HIDC + t], ae * ve);
    if (f == 0) atomicAdd(&den[(long)dn * NH + h], ae);
}

// out = gelu(msg/den) @ Wa + ba; x_new = beta*out + (1-beta)*x  (in-place safe)
__global__ void outproj_kernel(const float* __restrict__ msg, const float* __restrict__ den,
                               const float* __restrict__ xin,
                               const float* __restrict__ Wa, const float* __restrict__ ba,
                               const float* __restrict__ skip, float* __restrict__ xout)
{
    __shared__ float gsh[HIDC];
    int row = blockIdx.x, t = threadIdx.x;
    float dh = den[(long)row * NH + (t >> 4)];
    float hv = msg[(long)row * HIDC + t] / fmaxf(dh, 1e-16f);
    float g = 0.5f * hv * (1.f + tanhf(0.7978845608028654f * (hv + 0.044715f * hv * hv * hv)));
    gsh[t] = g;
    __syncthreads();
    float acc = ba[t];
    for (int k = 0; k < HIDC; ++k) acc = fmaf(gsh[k], Wa[k * HIDC + t], acc);
    float beta = 1.f / (1.f + expf(-skip[0]));
    float xo = xin[(long)row * HIDC + t];
    xout[(long)row * HIDC + t] = beta * acc + (1.f - beta) * xo;
}

// out[row, c] = x[row]·Wcls[c] + bcls[c];  4 groups of 32 lanes per row
__global__ void cls_kernel(const float* __restrict__ X, const float* __restrict__ Wc,
                           const float* __restrict__ bc, float* __restrict__ out)
{
    int row = blockIdx.x, t = threadIdx.x;
    int c = t >> 5, j = t & 31;
    const float* xr = X + (long)row * HIDC;
    const float* w = Wc + c * HIDC;
    float p = 0.f;
    for (int k = j; k < HIDC; k += 32) p = fmaf(xr[k], w[k], p);
    #pragma unroll
    for (int off = 16; off; off >>= 1) p += __shfl_xor(p, off, 32);
    if (j == 0) out[(long)row * NCLS + c] = p + bc[c];
}

template <typename T>
static void run_all(void* const* d_in, void* d_out, void* d_ws,
                    int Na, int Nb, int E, hipStream_t stream)
{
    const float* x_a    = (const float*)d_in[0];
    const float* x_b    = (const float*)d_in[1];
    const float* lin_W_a= (const float*)d_in[2];
    const float* lin_b_a= (const float*)d_in[3];
    const float* lin_W_b= (const float*)d_in[4];
    const float* lin_b_b= (const float*)d_in[5];
    const float* Wk     = (const float*)d_in[6];
    const float* bk     = (const float*)d_in[7];
    const float* Wq     = (const float*)d_in[8];
    const float* bq     = (const float*)d_in[9];
    const float* Wv     = (const float*)d_in[10];
    const float* bv     = (const float*)d_in[11];
    const float* arel   = (const float*)d_in[12];
    const float* mrel   = (const float*)d_in[13];
    const float* prel   = (const float*)d_in[14];
    const float* Wa     = (const float*)d_in[15];
    const float* ba     = (const float*)d_in[16];
    const float* skip   = (const float*)d_in[17];
    const float* Wcls   = (const float*)d_in[18];
    const float* bcls   = (const float*)d_in[19];
    const int* eptr[4] = {(const int*)d_in[20], (const int*)d_in[21],
                          (const int*)d_in[22], (const int*)d_in[23]};

    int Nn[2] = {Na, Nb};
    int Nmax = Na > Nb ? Na : Nb;

    // ---- workspace layout (byte-based) ----
    char* base = (char*)d_ws;
    float* x[2];
    x[0] = (float*)base; base += (size_t)Na * HIDC * 4;
    x[1] = (float*)base; base += (size_t)Nb * HIDC * 4;
    T *kb[2], *qb[2], *vb[2];
    for (int t = 0; t < 2; ++t) {
        kb[t] = (T*)base; base += (size_t)Nn[t] * HIDC * sizeof(T);
        qb[t] = (T*)base; base += (size_t)Nn[t] * HIDC * sizeof(T);
        vb[t] = (T*)base; base += (size_t)Nn[t] * HIDC * sizeof(T);
    }
    float* abuf = (float*)base; base += (size_t)2 * E * NH * 4;
    // amax, den, msg contiguous so one zero kernel covers all three
    unsigned* amax = (unsigned*)base; base += (size_t)Nmax * NH * 4;
    float* den  = (float*)base; base += (size_t)Nmax * NH * 4;
    float* msg  = (float*)base; base += (size_t)Nmax * HIDC * 4;
    long zero_words = (long)Nmax * (NH + NH + HIDC);

    // ---- input projections + ReLU ----
    rowgemm_relu<<<Na, HIDC, 0, stream>>>(x_a, lin_W_a, lin_b_a, x[0], 64);
    rowgemm_relu<<<Nb, HIDC, 0, stream>>>(x_b, lin_W_b, lin_b_b, x[1], 32);

    const float scale = 0.25f;  // 1/sqrt(D), D=16
    // relations: r0 aa(0->0), r1 ab(0->1), r2 ba(1->0), r3 bb(1->1)
    const int rs[4] = {0, 0, 1, 1};
    const int rd[4] = {0, 1, 0, 1};

    for (int l = 0; l < 2; ++l) {
        for (int t = 0; t < 2; ++t) {
            int wo = (l * 2 + t) * HIDC * HIDC, bo = (l * 2 + t) * HIDC;
            kqv_kernel<T><<<Nn[t], HIDC, 0, stream>>>(x[t], Wk + wo, bk + bo,
                                                      Wq + wo, bq + bo, Wv + wo, bv + bo,
                                                      kb[t], qb[t], vb[t]);
        }
        for (int dt = 0; dt < 2; ++dt) {
            zero_u32<<<2048, 256, 0, stream>>>(amax, zero_words);
            int slot = 0;
            for (int r = 0; r < 4; ++r) {
                if (rd[r] != dt) continue;
                const float* ar = arel + (size_t)(l * 4 + r) * NH * HD * HD;
                const float* pr = prel + (l * 4 + r) * NH;
                logits_kernel<T><<<E, HIDC, 0, stream>>>(kb[rs[r]], qb[dt],
                                                         eptr[r], eptr[r] + E,
                                                         ar, pr, abuf + (size_t)slot * E * NH,
                                                         amax, scale);
                ++slot;
            }
            slot = 0;
            for (int r = 0; r < 4; ++r) {
                if (rd[r] != dt) continue;
                const float* mr = mrel + (size_t)(l * 4 + r) * NH * HD * HD;
                agg_kernel<T><<<E, HIDC, 0, stream>>>(vb[rs[r]], eptr[r], eptr[r] + E,
                                                      mr, abuf + (size_t)slot * E * NH,
                                                      amax, den, msg);
                ++slot;
            }
            int wo = (l * 2 + dt) * HIDC * HIDC, bo = (l * 2 + dt) * HIDC;
            outproj_kernel<<<Nn[dt], HIDC, 0, stream>>>(msg, den, x[dt],
                                                        Wa + wo, ba + bo,
                                                        skip + (l * 2 + dt), x[dt]);
        }
    }

    cls_kernel<<<Na, HIDC, 0, stream>>>(x[0], Wcls, bcls, (float*)d_out);
}

extern "C" void kernel_launch(void* const* d_in, const int* in_sizes, int n_in,
                              void* d_out, int out_size, void* d_ws, size_t ws_size,
                              hipStream_t stream)
{
    int Na = in_sizes[0] / 64;
    int Nb = in_sizes[1] / 32;
    int E  = in_sizes[20] / 2;
    int Nmax = Na > Nb ? Na : Nb;

    size_t fixed = (size_t)(Na + Nb) * HIDC * 4      // x
                 + (size_t)2 * E * NH * 4            // abuf
                 + (size_t)Nmax * NH * 4 * 2         // amax + den
                 + (size_t)Nmax * HIDC * 4;          // msg
    size_t need_f32 = fixed + (size_t)3 * (Na + Nb) * HIDC * sizeof(float);

    if (ws_size >= need_f32)
        run_all<float>(d_in, d_out, d_ws, Na, Nb, E, stream);
    else
        run_all<__hip_bfloat16>(d_in, d_out, d_ws, Na, Nb, E, stream);
}

// Round 3
// 2210.500 us; speedup vs baseline: 1.3545x; 1.3545x over previous
//
#include <hip/hip_runtime.h>
#include <math.h>

#define HIDC 128
#define NH 8
#define HD 16
#define NCLS 4

// ---- ordered-float encoding for atomicMax on unsigned ----
__device__ __forceinline__ unsigned enc_f(float f) {
    unsigned b = __float_as_uint(f);
    return (b & 0x80000000u) ? ~b : (b | 0x80000000u);
}
__device__ __forceinline__ float dec_f(unsigned u) {
    unsigned b = (u & 0x80000000u) ? (u & 0x7fffffffu) : ~u;
    return __uint_as_float(b);
}
__device__ __forceinline__ float gelu_f(float h) {
    float z = 0.7978845608028654f * (h + 0.044715f * h * h * h);
    float t = 1.f - 2.f / (1.f + __expf(2.f * z));   // tanh(z)
    return 0.5f * h * (1.f + t);
}

__global__ void zero_u32(unsigned* __restrict__ p, long n)
{
    long i = (long)blockIdx.x * blockDim.x + threadIdx.x;
    long stride = (long)gridDim.x * blockDim.x;
    for (; i < n; i += stride) p[i] = 0u;
}

// Fold relation transforms into projection weights:
// Wt[bid][k][h*16+f] = sum_d W[k][h*16+d] * rel[h][d][f];  bt likewise from bias.
// bid = l*8 + r*2 + w  (w: 0=K/arel, 1=V/mrel); src type st = r>>1.
__global__ void fold_all(const float* __restrict__ Wk, const float* __restrict__ bk,
                         const float* __restrict__ Wv, const float* __restrict__ bv,
                         const float* __restrict__ arel, const float* __restrict__ mrel,
                         float* __restrict__ Wt, float* __restrict__ bt)
{
    __shared__ float rsh[NH * HD * HD];
    int bid = blockIdx.x;
    int w = bid & 1, r = (bid >> 1) & 3, l = bid >> 3;
    int st = r >> 1;
    const float* W   = (w ? Wv : Wk) + (size_t)(l * 2 + st) * HIDC * HIDC;
    const float* bb  = (w ? bv : bk) + (size_t)(l * 2 + st) * HIDC;
    const float* rel = (w ? mrel : arel) + (size_t)(l * 4 + r) * NH * HD * HD;
    float* wt  = Wt + (size_t)bid * HIDC * HIDC;
    float* btp = bt + (size_t)bid * HIDC;

    int t = threadIdx.x;
    for (int i = t; i < NH * HD * HD; i += 128) rsh[i] = rel[i];
    __syncthreads();
    int h = t >> 4, f = t & 15;
    const float* rh = rsh + h * HD * HD + f;   // rh[d*HD]
    for (int k = 0; k < HIDC; ++k) {
        float acc = 0.f;
        const float* wr = W + (size_t)k * HIDC + h * HD;
        #pragma unroll
        for (int d = 0; d < HD; ++d) acc = fmaf(wr[d], rh[d * HD], acc);
        wt[(size_t)k * HIDC + t] = acc;
    }
    float accb = 0.f;
    const float* br = bb + h * HD;
    #pragma unroll
    for (int d = 0; d < HD; ++d) accb = fmaf(br[d], rh[d * HD], accb);
    btp[t] = accb;
}

// ---- tiled f32 GEMM: C[N x 128] = EPI(A[N x K] @ W[K x 128] + bias) ----
// AMODE: 0 = plain A load, 1 = A := gelu(msg/den) on load (den per row,head)
// EPI:   0 = none, 1 = relu, 2 = blend: C = beta*o + (1-beta)*xold, beta=sigmoid(skip)
// block 256 thr, tile 64 rows x 128 cols, KT=16.
template <int AMODE, int EPI>
__global__ __launch_bounds__(256)
void gemm_tile(const float* __restrict__ A, const float* __restrict__ den,
               const float* __restrict__ W, const float* __restrict__ bias,
               const float* __restrict__ xold, const float* __restrict__ skipp,
               float* __restrict__ C, int N, int K)
{
    __shared__ float Xt[16][68];     // transposed X tile [k][row], pad 68 (16B-aligned rows)
    __shared__ float Ws[16][HIDC];   // W tile [k][col]
    int t = threadIdx.x;
    int cg = t & 31, rg = t >> 5;    // cols 4*cg..4*cg+3, rows 8*rg..8*rg+7
    int row0 = blockIdx.x * 64;

    float4 acc[8];
    #pragma unroll
    for (int i = 0; i < 8; ++i) acc[i] = make_float4(0.f, 0.f, 0.f, 0.f);

    for (int k0 = 0; k0 < K; k0 += 16) {
        // ---- load X tile (64 rows x 16 k), transposed into Xt ----
        {
            int r = t >> 2, c4 = (t & 3) * 4;
            int row = row0 + r;
            float4 v = make_float4(0.f, 0.f, 0.f, 0.f);
            if (row < N) {
                v = *(const float4*)(A + (size_t)row * K + k0 + c4);
                if (AMODE == 1) {
                    float dh = fmaxf(den[(size_t)row * NH + (k0 >> 4)], 1e-16f);
                    v.x = gelu_f(v.x / dh); v.y = gelu_f(v.y / dh);
                    v.z = gelu_f(v.z / dh); v.w = gelu_f(v.w / dh);
                }
            }
            Xt[c4 + 0][r] = v.x; Xt[c4 + 1][r] = v.y;
            Xt[c4 + 2][r] = v.z; Xt[c4 + 3][r] = v.w;
        }
        // ---- load W tile (16 k x 128 cols) ----
        #pragma unroll
        for (int j = 0; j < 2; ++j) {
            int idx = t + j * 256;
            int r = idx >> 5, c4 = (idx & 31) * 4;
            *(float4*)&Ws[r][c4] = *(const float4*)(W + (size_t)(k0 + r) * HIDC + c4);
        }
        __syncthreads();
        #pragma unroll
        for (int kk = 0; kk < 16; ++kk) {
            float4 w = *(const float4*)&Ws[kk][cg * 4];
            float4 xa = *(const float4*)&Xt[kk][rg * 8];
            float4 xb = *(const float4*)&Xt[kk][rg * 8 + 4];
            acc[0].x = fmaf(xa.x, w.x, acc[0].x); acc[0].y = fmaf(xa.x, w.y, acc[0].y);
            acc[0].z = fmaf(xa.x, w.z, acc[0].z); acc[0].w = fmaf(xa.x, w.w, acc[0].w);
            acc[1].x = fmaf(xa.y, w.x, acc[1].x); acc[1].y = fmaf(xa.y, w.y, acc[1].y);
            acc[1].z = fmaf(xa.y, w.z, acc[1].z); acc[1].w = fmaf(xa.y, w.w, acc[1].w);
            acc[2].x = fmaf(xa.z, w.x, acc[2].x); acc[2].y = fmaf(xa.z, w.y, acc[2].y);
            acc[2].z = fmaf(xa.z, w.z, acc[2].z); acc[2].w = fmaf(xa.z, w.w, acc[2].w);
            acc[3].x = fmaf(xa.w, w.x, acc[3].x); acc[3].y = fmaf(xa.w, w.y, acc[3].y);
            acc[3].z = fmaf(xa.w, w.z, acc[3].z); acc[3].w = fmaf(xa.w, w.w, acc[3].w);
            acc[4].x = fmaf(xb.x, w.x, acc[4].x); acc[4].y = fmaf(xb.x, w.y, acc[4].y);
            acc[4].z = fmaf(xb.x, w.z, acc[4].z); acc[4].w = fmaf(xb.x, w.w, acc[4].w);
            acc[5].x = fmaf(xb.y, w.x, acc[5].x); acc[5].y = fmaf(xb.y, w.y, acc[5].y);
            acc[5].z = fmaf(xb.y, w.z, acc[5].z); acc[5].w = fmaf(xb.y, w.w, acc[5].w);
            acc[6].x = fmaf(xb.z, w.x, acc[6].x); acc[6].y = fmaf(xb.z, w.y, acc[6].y);
            acc[6].z = fmaf(xb.z, w.z, acc[6].z); acc[6].w = fmaf(xb.z, w.w, acc[6].w);
            acc[7].x = fmaf(xb.w, w.x, acc[7].x); acc[7].y = fmaf(xb.w, w.y, acc[7].y);
            acc[7].z = fmaf(xb.w, w.z, acc[7].z); acc[7].w = fmaf(xb.w, w.w, acc[7].w);
        }
        __syncthreads();
    }

    float4 b4 = *(const float4*)&bias[cg * 4];
    float beta = 0.f;
    if (EPI == 2) beta = 1.f / (1.f + __expf(-skipp[0]));
    #pragma unroll
    for (int i = 0; i < 8; ++i) {
        int row = row0 + rg * 8 + i;
        if (row >= N) continue;
        float4 o;
        o.x = acc[i].x + b4.x; o.y = acc[i].y + b4.y;
        o.z = acc[i].z + b4.z; o.w = acc[i].w + b4.w;
        if (EPI == 1) {
            o.x = fmaxf(o.x, 0.f); o.y = fmaxf(o.y, 0.f);
            o.z = fmaxf(o.z, 0.f); o.w = fmaxf(o.w, 0.f);
        }
        if (EPI == 2) {
            float4 xo = *(const float4*)(xold + (size_t)row * HIDC + cg * 4);
            o.x = beta * o.x + (1.f - beta) * xo.x;
            o.y = beta * o.y + (1.f - beta) * xo.y;
            o.z = beta * o.z + (1.f - beta) * xo.z;
            o.w = beta * o.w + (1.f - beta) * xo.w;
        }
        *(float4*)(C + (size_t)row * HIDC + cg * 4) = o;
    }
}

// ---- per-edge logits: one wave per edge; lane = h*8 + f2/2 ----
__global__ __launch_bounds__(256)
void logits_kernel(const float* __restrict__ Kt, const float* __restrict__ Q,
                   const int* __restrict__ src, const int* __restrict__ dst,
                   const float* __restrict__ prel, float scale,
                   float* __restrict__ aout, unsigned* __restrict__ amax, int E)
{
    int e = blockIdx.x * 4 + (threadIdx.x >> 6);
    if (e >= E) return;
    int lane = threadIdx.x & 63;
    int h = lane >> 3, f2 = (lane & 7) * 2;
    int s = src[e], dn = dst[e];
    float2 kv = *(const float2*)(Kt + (size_t)s * HIDC + h * HD + f2);
    float2 qv = *(const float2*)(Q + (size_t)dn * HIDC + h * HD + f2);
    float part = kv.x * qv.x + kv.y * qv.y;
    part += __shfl_xor(part, 4, 8);
    part += __shfl_xor(part, 2, 8);
    part += __shfl_xor(part, 1, 8);
    if ((lane & 7) == 0) {
        float a = part * prel[h] * scale;
        aout[(size_t)e * NH + h] = a;
        atomicMax(&amax[(size_t)dn * NH + h], enc_f(a));
    }
}

// ---- per-edge aggregation: ae = exp(a - amax); den += ae; msg += ae * Vt[src] ----
__global__ __launch_bounds__(256)
void agg_kernel(const float* __restrict__ Vt,
                const int* __restrict__ src, const int* __restrict__ dst,
                const float* __restrict__ ain, const unsigned* __restrict__ amax,
                float* __restrict__ den, float* __restrict__ msg, int E)
{
    int e = blockIdx.x * 4 + (threadIdx.x >> 6);
    if (e >= E) return;
    int lane = threadIdx.x & 63;
    int h = lane >> 3, f2 = (lane & 7) * 2;
    int s = src[e], dn = dst[e];
    float2 vv = *(const float2*)(Vt + (size_t)s * HIDC + h * HD + f2);
    float a = ain[(size_t)e * NH + h];
    float m = dec_f(amax[(size_t)dn * NH + h]);
    float ae = __expf(a - m);
    float* mp = msg + (size_t)dn * HIDC + h * HD + f2;
    atomicAdd(mp, ae * vv.x);
    atomicAdd(mp + 1, ae * vv.y);
    if ((lane & 7) == 0) atomicAdd(den + (size_t)dn * NH + h, ae);
}

// out[row, c] = x[row]·Wcls[c] + bcls[c]
__global__ __launch_bounds__(128)
void cls_kernel(const float* __restrict__ X, const float* __restrict__ Wc,
                const float* __restrict__ bc, float* __restrict__ out)
{
    int row = blockIdx.x, t = threadIdx.x;
    int c = t >> 5, j = t & 31;
    const float* xr = X + (size_t)row * HIDC;
    const float* w = Wc + c * HIDC;
    float p = 0.f;
    for (int k = j; k < HIDC; k += 32) p = fmaf(xr[k], w[k], p);
    #pragma unroll
    for (int off = 16; off; off >>= 1) p += __shfl_xor(p, off, 32);
    if (j == 0) out[(size_t)row * NCLS + c] = p + bc[c];
}

extern "C" void kernel_launch(void* const* d_in, const int* in_sizes, int n_in,
                              void* d_out, int out_size, void* d_ws, size_t ws_size,
                              hipStream_t stream)
{
    const float* x_a    = (const float*)d_in[0];
    const float* x_b    = (const float*)d_in[1];
    const float* lin_W_a= (const float*)d_in[2];
    const float* lin_b_a= (const float*)d_in[3];
    const float* lin_W_b= (const float*)d_in[4];
    const float* lin_b_b= (const float*)d_in[5];
    const float* Wk     = (const float*)d_in[6];
    const float* bk     = (const float*)d_in[7];
    const float* Wq     = (const float*)d_in[8];
    const float* bq     = (const float*)d_in[9];
    const float* Wv     = (const float*)d_in[10];
    const float* bv     = (const float*)d_in[11];
    const float* arel   = (const float*)d_in[12];
    const float* mrel   = (const float*)d_in[13];
    const float* prel   = (const float*)d_in[14];
    const float* Wa     = (const float*)d_in[15];
    const float* ba     = (const float*)d_in[16];
    const float* skip   = (const float*)d_in[17];
    const float* Wcls   = (const float*)d_in[18];
    const float* bcls   = (const float*)d_in[19];
    const int* eptr[4] = {(const int*)d_in[20], (const int*)d_in[21],
                          (const int*)d_in[22], (const int*)d_in[23]};
    int Ee[4] = {in_sizes[20] / 2, in_sizes[21] / 2, in_sizes[22] / 2, in_sizes[23] / 2};

    int Na = in_sizes[0] / 64;
    int Nb = in_sizes[1] / 32;
    int Nn[2] = {Na, Nb};
    int Nmax = Na > Nb ? Na : Nb;
    int Emax = 0; for (int r = 0; r < 4; ++r) Emax = Ee[r] > Emax ? Ee[r] : Emax;

    // ---- workspace layout ----
    char* base = (char*)d_ws;
    float* xbuf[2][2];   // [set][type]
    for (int s = 0; s < 2; ++s)
        for (int t = 0; t < 2; ++t) { xbuf[s][t] = (float*)base; base += (size_t)Nn[t] * HIDC * 4; }
    float* qbuf = (float*)base; base += (size_t)Nmax * HIDC * 4;
    float* ktbuf[2];
    ktbuf[0] = (float*)base; base += (size_t)Nmax * HIDC * 4;
    ktbuf[1] = (float*)base; base += (size_t)Nmax * HIDC * 4;
    float* abuf = (float*)base; base += (size_t)2 * Emax * NH * 4;
    unsigned* amax = (unsigned*)base; base += (size_t)Nmax * NH * 4;
    float* den = (float*)base; base += (size_t)Nmax * NH * 4;
    float* msg = (float*)base; base += (size_t)Nmax * HIDC * 4;
    float* Wt = (float*)base; base += (size_t)16 * HIDC * HIDC * 4;
    float* bt = (float*)base; base += (size_t)16 * HIDC * 4;
    long zero_words = (long)Nmax * (NH + NH + HIDC);

    // ---- fold relation transforms into K/V projection weights ----
    fold_all<<<16, 128, 0, stream>>>(Wk, bk, Wv, bv, arel, mrel, Wt, bt);

    // ---- input projections + ReLU ----
    int ga = (Na + 63) / 64, gb = (Nb + 63) / 64;
    gemm_tile<0, 1><<<ga, 256, 0, stream>>>(x_a, nullptr, lin_W_a, lin_b_a,
                                            nullptr, nullptr, xbuf[0][0], Na, 64);
    gemm_tile<0, 1><<<gb, 256, 0, stream>>>(x_b, nullptr, lin_W_b, lin_b_b,
                                            nullptr, nullptr, xbuf[0][1], Nb, 32);

    const float scale = 0.25f;   // 1/sqrt(16)
    const int rs[4] = {0, 0, 1, 1};
    const int rd[4] = {0, 1, 0, 1};
    int cur = 0;

    for (int l = 0; l < 2; ++l) {
        int nxt = cur ^ 1;
        for (int dt = 0; dt < 2; ++dt) {
            float** xc = xbuf[cur];
            int gN = (Nn[dt] + 63) / 64;
            // Q projection for dst type
            gemm_tile<0, 0><<<gN, 256, 0, stream>>>(xc[dt], nullptr,
                                                    Wq + (size_t)(l * 2 + dt) * HIDC * HIDC,
                                                    bq + (l * 2 + dt) * HIDC,
                                                    nullptr, nullptr, qbuf, Nn[dt], HIDC);
            // K-tilde for the two relations targeting dt
            int rel2[2], nr = 0;
            for (int r = 0; r < 4; ++r) if (rd[r] == dt) rel2[nr++] = r;
            for (int i = 0; i < 2; ++i) {
                int r = rel2[i], st = rs[r];
                int gS = (Nn[st] + 63) / 64;
                gemm_tile<0, 0><<<gS, 256, 0, stream>>>(xc[st], nullptr,
                                                        Wt + (size_t)(l * 8 + r * 2 + 0) * HIDC * HIDC,
                                                        bt + (size_t)(l * 8 + r * 2 + 0) * HIDC,
                                                        nullptr, nullptr, ktbuf[i], Nn[st], HIDC);
            }
            zero_u32<<<1024, 256, 0, stream>>>(amax, zero_words);
            for (int i = 0; i < 2; ++i) {
                int r = rel2[i];
                logits_kernel<<<(Ee[r] + 3) / 4, 256, 0, stream>>>(
                    ktbuf[i], qbuf, eptr[r], eptr[r] + Ee[r],
                    prel + (l * 4 + r) * NH, scale,
                    abuf + (size_t)i * Emax * NH, amax, Ee[r]);
            }
            // V-tilde overwrites ktbuf after logits consumed them
            for (int i = 0; i < 2; ++i) {
                int r = rel2[i], st = rs[r];
                int gS = (Nn[st] + 63) / 64;
                gemm_tile<0, 0><<<gS, 256, 0, stream>>>(xc[st], nullptr,
                                                        Wt + (size_t)(l * 8 + r * 2 + 1) * HIDC * HIDC,
                                                        bt + (size_t)(l * 8 + r * 2 + 1) * HIDC,
                                                        nullptr, nullptr, ktbuf[i], Nn[st], HIDC);
            }
            for (int i = 0; i < 2; ++i) {
                int r = rel2[i];
                agg_kernel<<<(Ee[r] + 3) / 4, 256, 0, stream>>>(
                    ktbuf[i], eptr[r], eptr[r] + Ee[r],
                    abuf + (size_t)i * Emax * NH, amax, den, msg, Ee[r]);
            }
            // out = gelu(msg/den) @ Wa + ba, blended with skip gate -> next x
            gemm_tile<1, 2><<<gN, 256, 0, stream>>>(msg, den,
                                                    Wa + (size_t)(l * 2 + dt) * HIDC * HIDC,
                                                    ba + (l * 2 + dt) * HIDC,
                                                    xc[dt], skip + (l * 2 + dt),
                                                    xbuf[nxt][dt], Nn[dt], HIDC);
        }
        cur ^= 1;
    }

    cls_kernel<<<Na, 128, 0, stream>>>(xbuf[cur][0], Wcls, bcls, (float*)d_out);
}

// Round 4
// 1162.545 us; speedup vs baseline: 2.5754x; 1.9014x over previous
//
#include <hip/hip_runtime.h>
#include <math.h>

#define HIDC 128
#define NH 8
#define HD 16
#define NCLS 4

__device__ __forceinline__ float gelu_f(float h) {
    float z = 0.7978845608028654f * (h + 0.044715f * h * h * h);
    float t = 1.f - 2.f / (1.f + __expf(2.f * z));   // tanh(z)
    return 0.5f * h * (1.f + t);
}

__global__ void zero_u32(unsigned* __restrict__ p, long n)
{
    long i = (long)blockIdx.x * blockDim.x + threadIdx.x;
    long stride = (long)gridDim.x * blockDim.x;
    for (; i < n; i += stride) p[i] = 0u;
}

// Fold relation transforms into projection weights:
// Wt[bid][k][h*16+f] = sum_d W[k][h*16+d] * rel[h][d][f];  bt likewise.
// bid = l*8 + r*2 + w  (w: 0=K/arel, 1=V/mrel); src type st = r>>1.
__global__ void fold_all(const float* __restrict__ Wk, const float* __restrict__ bk,
                         const float* __restrict__ Wv, const float* __restrict__ bv,
                         const float* __restrict__ arel, const float* __restrict__ mrel,
                         float* __restrict__ Wt, float* __restrict__ bt)
{
    __shared__ float rsh[NH * HD * HD];
    int bid = blockIdx.x;
    int w = bid & 1, r = (bid >> 1) & 3, l = bid >> 3;
    int st = r >> 1;
    const float* W   = (w ? Wv : Wk) + (size_t)(l * 2 + st) * HIDC * HIDC;
    const float* bb  = (w ? bv : bk) + (size_t)(l * 2 + st) * HIDC;
    const float* rel = (w ? mrel : arel) + (size_t)(l * 4 + r) * NH * HD * HD;
    float* wt  = Wt + (size_t)bid * HIDC * HIDC;
    float* btp = bt + (size_t)bid * HIDC;

    int t = threadIdx.x;
    for (int i = t; i < NH * HD * HD; i += 128) rsh[i] = rel[i];
    __syncthreads();
    int h = t >> 4, f = t & 15;
    const float* rh = rsh + h * HD * HD + f;
    for (int k = 0; k < HIDC; ++k) {
        float acc = 0.f;
        const float* wr = W + (size_t)k * HIDC + h * HD;
        #pragma unroll
        for (int d = 0; d < HD; ++d) acc = fmaf(wr[d], rh[d * HD], acc);
        wt[(size_t)k * HIDC + t] = acc;
    }
    float accb = 0.f;
    const float* br = bb + h * HD;
    #pragma unroll
    for (int d = 0; d < HD; ++d) accb = fmaf(br[d], rh[d * HD], accb);
    btp[t] = accb;
}

// ---- CSR build ----
__global__ void hist_kernel(const int* __restrict__ d1, int E1,
                            const int* __restrict__ d2, int E2,
                            unsigned* __restrict__ cnt)
{
    int i = blockIdx.x * blockDim.x + threadIdx.x;
    int tot = E1 + E2;
    int stride = gridDim.x * blockDim.x;
    for (; i < tot; i += stride) {
        int d = (i < E1) ? d1[i] : d2[i - E1];
        atomicAdd(&cnt[d], 1u);
    }
}

__global__ __launch_bounds__(1024)
void scan_kernel(unsigned* __restrict__ cnt, int* __restrict__ rowptr,
                 unsigned* __restrict__ cursor, int Nmax, int n0, int n1)
{
    int dt = blockIdx.x;
    unsigned* c = cnt + (size_t)dt * Nmax;
    int* rp = rowptr + (size_t)dt * (Nmax + 1);
    unsigned* cur = cursor + (size_t)dt * Nmax;
    int n = dt ? n1 : n0;
    __shared__ unsigned part[1024];
    int tid = threadIdx.x;
    int chunk = (n + 1023) / 1024;
    int start = tid * chunk;
    unsigned sum = 0;
    for (int j = 0; j < chunk; ++j) { int i = start + j; if (i < n) sum += c[i]; }
    part[tid] = sum;
    __syncthreads();
    for (int off = 1; off < 1024; off <<= 1) {
        unsigned t = (tid >= off) ? part[tid - off] : 0u;
        __syncthreads();
        part[tid] += t;
        __syncthreads();
    }
    unsigned run = part[tid] - sum;   // exclusive prefix
    for (int j = 0; j < chunk; ++j) {
        int i = start + j;
        if (i < n) { rp[i] = (int)run; cur[i] = run; run += c[i]; }
    }
    if (tid == 1023) rp[n] = (int)part[1023];
}

__global__ void scatter_kernel(const int* __restrict__ s1, const int* __restrict__ d1, int E1,
                               const int* __restrict__ s2, const int* __restrict__ d2, int E2,
                               unsigned* __restrict__ cursor, unsigned* __restrict__ adj)
{
    int i = blockIdx.x * blockDim.x + threadIdx.x;
    int tot = E1 + E2;
    int stride = gridDim.x * blockDim.x;
    for (; i < tot; i += stride) {
        int s, d; unsigned rb;
        if (i < E1) { s = s1[i]; d = d1[i]; rb = 0u; }
        else        { s = s2[i - E1]; d = d2[i - E1]; rb = 1u << 24; }
        unsigned pos = atomicAdd(&cursor[d], 1u);
        adj[pos] = (unsigned)s | rb;
    }
}

// ---- tiled f32 GEMM: C[N x 128] = EPI(A[N x K] @ W[K x 128] + bias) ----
// EPI: 0 = none, 1 = relu, 2 = blend: C = beta*o + (1-beta)*xold
#define GEMM_INNER(ACC, WT)                                                        \
    {                                                                              \
        float4 w = *(const float4*)&WT[kk][cg * 4];                                \
        ACC[0].x = fmaf(xa.x, w.x, ACC[0].x); ACC[0].y = fmaf(xa.x, w.y, ACC[0].y);\
        ACC[0].z = fmaf(xa.x, w.z, ACC[0].z); ACC[0].w = fmaf(xa.x, w.w, ACC[0].w);\
        ACC[1].x = fmaf(xa.y, w.x, ACC[1].x); ACC[1].y = fmaf(xa.y, w.y, ACC[1].y);\
        ACC[1].z = fmaf(xa.y, w.z, ACC[1].z); ACC[1].w = fmaf(xa.y, w.w, ACC[1].w);\
        ACC[2].x = fmaf(xa.z, w.x, ACC[2].x); ACC[2].y = fmaf(xa.z, w.y, ACC[2].y);\
        ACC[2].z = fmaf(xa.z, w.z, ACC[2].z); ACC[2].w = fmaf(xa.z, w.w, ACC[2].w);\
        ACC[3].x = fmaf(xa.w, w.x, ACC[3].x); ACC[3].y = fmaf(xa.w, w.y, ACC[3].y);\
        ACC[3].z = fmaf(xa.w, w.z, ACC[3].z); ACC[3].w = fmaf(xa.w, w.w, ACC[3].w);\
        ACC[4].x = fmaf(xb.x, w.x, ACC[4].x); ACC[4].y = fmaf(xb.x, w.y, ACC[4].y);\
        ACC[4].z = fmaf(xb.x, w.z, ACC[4].z); ACC[4].w = fmaf(xb.x, w.w, ACC[4].w);\
        ACC[5].x = fmaf(xb.y, w.x, ACC[5].x); ACC[5].y = fmaf(xb.y, w.y, ACC[5].y);\
        ACC[5].z = fmaf(xb.y, w.z, ACC[5].z); ACC[5].w = fmaf(xb.y, w.w, ACC[5].w);\
        ACC[6].x = fmaf(xb.z, w.x, ACC[6].x); ACC[6].y = fmaf(xb.z, w.y, ACC[6].y);\
        ACC[6].z = fmaf(xb.z, w.z, ACC[6].z); ACC[6].w = fmaf(xb.z, w.w, ACC[6].w);\
        ACC[7].x = fmaf(xb.w, w.x, ACC[7].x); ACC[7].y = fmaf(xb.w, w.y, ACC[7].y);\
        ACC[7].z = fmaf(xb.w, w.z, ACC[7].z); ACC[7].w = fmaf(xb.w, w.w, ACC[7].w);\
    }

template <int EPI>
__global__ __launch_bounds__(256)
void gemm_tile(const float* __restrict__ A, const float* __restrict__ W,
               const float* __restrict__ bias, const float* __restrict__ xold,
               const float* __restrict__ skipp, float* __restrict__ C, int N, int K)
{
    __shared__ float Xt[16][68];
    __shared__ float Ws[16][HIDC];
    int t = threadIdx.x;
    int cg = t & 31, rg = t >> 5;
    int row0 = blockIdx.x * 64;

    float4 acc[8];
    #pragma unroll
    for (int i = 0; i < 8; ++i) acc[i] = make_float4(0.f, 0.f, 0.f, 0.f);

    for (int k0 = 0; k0 < K; k0 += 16) {
        {
            int r = t >> 2, c4 = (t & 3) * 4;
            int row = row0 + r;
            float4 v = make_float4(0.f, 0.f, 0.f, 0.f);
            if (row < N) v = *(const float4*)(A + (size_t)row * K + k0 + c4);
            Xt[c4 + 0][r] = v.x; Xt[c4 + 1][r] = v.y;
            Xt[c4 + 2][r] = v.z; Xt[c4 + 3][r] = v.w;
        }
        #pragma unroll
        for (int j = 0; j < 2; ++j) {
            int idx = t + j * 256;
            int r = idx >> 5, c4 = (idx & 31) * 4;
            *(float4*)&Ws[r][c4] = *(const float4*)(W + (size_t)(k0 + r) * HIDC + c4);
        }
        __syncthreads();
        #pragma unroll
        for (int kk = 0; kk < 16; ++kk) {
            float4 xa = *(const float4*)&Xt[kk][rg * 8];
            float4 xb = *(const float4*)&Xt[kk][rg * 8 + 4];
            GEMM_INNER(acc, Ws)
        }
        __syncthreads();
    }

    float4 b4 = *(const float4*)&bias[cg * 4];
    float beta = 0.f;
    if (EPI == 2) beta = 1.f / (1.f + __expf(-skipp[0]));
    #pragma unroll
    for (int i = 0; i < 8; ++i) {
        int row = row0 + rg * 8 + i;
        if (row >= N) continue;
        float4 o;
        o.x = acc[i].x + b4.x; o.y = acc[i].y + b4.y;
        o.z = acc[i].z + b4.z; o.w = acc[i].w + b4.w;
        if (EPI == 1) {
            o.x = fmaxf(o.x, 0.f); o.y = fmaxf(o.y, 0.f);
            o.z = fmaxf(o.z, 0.f); o.w = fmaxf(o.w, 0.f);
        }
        if (EPI == 2) {
            float4 xo = *(const float4*)(xold + (size_t)row * HIDC + cg * 4);
            o.x = beta * o.x + (1.f - beta) * xo.x;
            o.y = beta * o.y + (1.f - beta) * xo.y;
            o.z = beta * o.z + (1.f - beta) * xo.z;
            o.w = beta * o.w + (1.f - beta) * xo.w;
        }
        *(float4*)(C + (size_t)row * HIDC + cg * 4) = o;
    }
}

// dual-output GEMM: C1 = A@W1+b1, C2 = A@W2+b2 (reads A tile once)
__global__ __launch_bounds__(256)
void gemm_dual(const float* __restrict__ A,
               const float* __restrict__ W1, const float* __restrict__ b1,
               const float* __restrict__ W2, const float* __restrict__ b2,
               float* __restrict__ C1, float* __restrict__ C2, int N, int K)
{
    __shared__ float Xt[16][68];
    __shared__ float Ws1[16][HIDC];
    __shared__ float Ws2[16][HIDC];
    int t = threadIdx.x;
    int cg = t & 31, rg = t >> 5;
    int row0 = blockIdx.x * 64;

    float4 acc1[8], acc2[8];
    #pragma unroll
    for (int i = 0; i < 8; ++i) {
        acc1[i] = make_float4(0.f, 0.f, 0.f, 0.f);
        acc2[i] = make_float4(0.f, 0.f, 0.f, 0.f);
    }

    for (int k0 = 0; k0 < K; k0 += 16) {
        {
            int r = t >> 2, c4 = (t & 3) * 4;
            int row = row0 + r;
            float4 v = make_float4(0.f, 0.f, 0.f, 0.f);
            if (row < N) v = *(const float4*)(A + (size_t)row * K + k0 + c4);
            Xt[c4 + 0][r] = v.x; Xt[c4 + 1][r] = v.y;
            Xt[c4 + 2][r] = v.z; Xt[c4 + 3][r] = v.w;
        }
        #pragma unroll
        for (int j = 0; j < 2; ++j) {
            int idx = t + j * 256;
            int r = idx >> 5, c4 = (idx & 31) * 4;
            *(float4*)&Ws1[r][c4] = *(const float4*)(W1 + (size_t)(k0 + r) * HIDC + c4);
            *(float4*)&Ws2[r][c4] = *(const float4*)(W2 + (size_t)(k0 + r) * HIDC + c4);
        }
        __syncthreads();
        #pragma unroll
        for (int kk = 0; kk < 16; ++kk) {
            float4 xa = *(const float4*)&Xt[kk][rg * 8];
            float4 xb = *(const float4*)&Xt[kk][rg * 8 + 4];
            GEMM_INNER(acc1, Ws1)
            GEMM_INNER(acc2, Ws2)
        }
        __syncthreads();
    }

    float4 ba = *(const float4*)&b1[cg * 4];
    float4 bb = *(const float4*)&b2[cg * 4];
    #pragma unroll
    for (int i = 0; i < 8; ++i) {
        int row = row0 + rg * 8 + i;
        if (row >= N) continue;
        float4 o1, o2;
        o1.x = acc1[i].x + ba.x; o1.y = acc1[i].y + ba.y;
        o1.z = acc1[i].z + ba.z; o1.w = acc1[i].w + ba.w;
        o2.x = acc2[i].x + bb.x; o2.y = acc2[i].y + bb.y;
        o2.z = acc2[i].z + bb.z; o2.w = acc2[i].w + bb.w;
        *(float4*)(C1 + (size_t)row * HIDC + cg * 4) = o1;
        *(float4*)(C2 + (size_t)row * HIDC + cg * 4) = o2;
    }
}

// ---- fused per-destination online-softmax aggregation ----
// one wave per dst node; lane = 2 channels; head h = lane>>3 (8 lanes/head).
// msg[node] = gelu( softmax-weighted sum of vt rows )
__global__ __launch_bounds__(256)
void agg_fused(const float* __restrict__ Q,
               const float* __restrict__ ktA, const float* __restrict__ vtA,
               const float* __restrict__ ktB, const float* __restrict__ vtB,
               const int* __restrict__ rowptr, const unsigned* __restrict__ adj,
               const float* __restrict__ prelA, const float* __restrict__ prelB,
               float scale, float* __restrict__ msg, int N)
{
    int node = blockIdx.x * 4 + (threadIdx.x >> 6);
    if (node >= N) return;
    int lane = threadIdx.x & 63;
    int h = lane >> 3;
    float spA = prelA[h] * scale, spB = prelB[h] * scale;
    float2 qv = *(const float2*)(Q + (size_t)node * HIDC + lane * 2);
    int beg = rowptr[node], end = rowptr[node + 1];
    float m = -INFINITY, s = 0.f;
    float accx = 0.f, accy = 0.f;
    for (int i = beg; i < end; ++i) {
        unsigned ent = adj[i];
        int src = (int)(ent & 0xFFFFFFu);
        int rl = (int)(ent >> 24);
        const float* kt = rl ? ktB : ktA;
        const float* vt = rl ? vtB : vtA;
        float2 kv = *(const float2*)(kt + (size_t)src * HIDC + lane * 2);
        float2 vv = *(const float2*)(vt + (size_t)src * HIDC + lane * 2);
        float p = kv.x * qv.x + kv.y * qv.y;
        p += __shfl_xor(p, 1, 8);
        p += __shfl_xor(p, 2, 8);
        p += __shfl_xor(p, 4, 8);
        float a = p * (rl ? spB : spA);
        float mn = fmaxf(m, a);
        float c = __expf(m - mn);
        float pe = __expf(a - mn);
        s = s * c + pe;
        accx = accx * c + pe * vv.x;
        accy = accy * c + pe * vv.y;
        m = mn;
    }
    float inv = 1.f / fmaxf(s, 1e-16f);
    float2 o;
    o.x = gelu_f(accx * inv);
    o.y = gelu_f(accy * inv);
    *(float2*)(msg + (size_t)node * HIDC + lane * 2) = o;
}

// out[row, c] = x[row]·Wcls[c] + bcls[c]
__global__ __launch_bounds__(128)
void cls_kernel(const float* __restrict__ X, const float* __restrict__ Wc,
                const float* __restrict__ bc, float* __restrict__ out)
{
    int row = blockIdx.x, t = threadIdx.x;
    int c = t >> 5, j = t & 31;
    const float* xr = X + (size_t)row * HIDC;
    const float* w = Wc + c * HIDC;
    float p = 0.f;
    for (int k = j; k < HIDC; k += 32) p = fmaf(xr[k], w[k], p);
    #pragma unroll
    for (int off = 16; off; off >>= 1) p += __shfl_xor(p, off, 32);
    if (j == 0) out[(size_t)row * NCLS + c] = p + bc[c];
}

extern "C" void kernel_launch(void* const* d_in, const int* in_sizes, int n_in,
                              void* d_out, int out_size, void* d_ws, size_t ws_size,
                              hipStream_t stream)
{
    const float* x_a    = (const float*)d_in[0];
    const float* x_b    = (const float*)d_in[1];
    const float* lin_W_a= (const float*)d_in[2];
    const float* lin_b_a= (const float*)d_in[3];
    const float* lin_W_b= (const float*)d_in[4];
    const float* lin_b_b= (const float*)d_in[5];
    const float* Wk     = (const float*)d_in[6];
    const float* bk     = (const float*)d_in[7];
    const float* Wq     = (const float*)d_in[8];
    const float* bq     = (const float*)d_in[9];
    const float* Wv     = (const float*)d_in[10];
    const float* bv     = (const float*)d_in[11];
    const float* arel   = (const float*)d_in[12];
    const float* mrel   = (const float*)d_in[13];
    const float* prel   = (const float*)d_in[14];
    const float* Wa     = (const float*)d_in[15];
    const float* ba     = (const float*)d_in[16];
    const float* skip   = (const float*)d_in[17];
    const float* Wcls   = (const float*)d_in[18];
    const float* bcls   = (const float*)d_in[19];
    const int* eptr[4] = {(const int*)d_in[20], (const int*)d_in[21],
                          (const int*)d_in[22], (const int*)d_in[23]};
    int Ee[4] = {in_sizes[20] / 2, in_sizes[21] / 2, in_sizes[22] / 2, in_sizes[23] / 2};

    int Na = in_sizes[0] / 64;
    int Nb = in_sizes[1] / 32;
    int Nn[2] = {Na, Nb};
    int Nmax = Na > Nb ? Na : Nb;

    // ---- workspace layout ----
    char* base = (char*)d_ws;
    float* x[2];
    x[0] = (float*)base; base += (size_t)Na * HIDC * 4;
    x[1] = (float*)base; base += (size_t)Nb * HIDC * 4;
    float* qbuf = (float*)base; base += (size_t)Nmax * HIDC * 4;
    float* kt[2]; float* vt[2];
    for (int i = 0; i < 2; ++i) {
        kt[i] = (float*)base; base += (size_t)Nmax * HIDC * 4;
        vt[i] = (float*)base; base += (size_t)Nmax * HIDC * 4;
    }
    float* msg = (float*)base; base += (size_t)Nmax * HIDC * 4;
    float* Wt = (float*)base; base += (size_t)16 * HIDC * HIDC * 4;
    float* bt = (float*)base; base += (size_t)16 * HIDC * 4;
    unsigned* cnt = (unsigned*)base; base += (size_t)2 * Nmax * 4;
    unsigned* cursor = (unsigned*)base; base += (size_t)2 * Nmax * 4;
    int* rowptr = (int*)base; base += (size_t)2 * (Nmax + 1) * 4;
    unsigned* adj0 = (unsigned*)base; base += (size_t)(Ee[0] + Ee[2]) * 4;
    unsigned* adj1 = (unsigned*)base; base += (size_t)(Ee[1] + Ee[3]) * 4;

    // ---- fold relation transforms into K/V projection weights (once) ----
    fold_all<<<16, 128, 0, stream>>>(Wk, bk, Wv, bv, arel, mrel, Wt, bt);

    // ---- CSR build (once; dt=0 merges rel {aa,ba}, dt=1 merges {ab,bb}) ----
    zero_u32<<<512, 256, 0, stream>>>(cnt, (long)2 * Nmax);
    hist_kernel<<<1024, 256, 0, stream>>>(eptr[0] + Ee[0], Ee[0], eptr[2] + Ee[2], Ee[2], cnt);
    hist_kernel<<<1024, 256, 0, stream>>>(eptr[1] + Ee[1], Ee[1], eptr[3] + Ee[3], Ee[3], cnt + Nmax);
    scan_kernel<<<2, 1024, 0, stream>>>(cnt, rowptr, cursor, Nmax, Na, Nb);
    scatter_kernel<<<1024, 256, 0, stream>>>(eptr[0], eptr[0] + Ee[0], Ee[0],
                                             eptr[2], eptr[2] + Ee[2], Ee[2], cursor, adj0);
    scatter_kernel<<<1024, 256, 0, stream>>>(eptr[1], eptr[1] + Ee[1], Ee[1],
                                             eptr[3], eptr[3] + Ee[3], Ee[3], cursor + Nmax, adj1);

    // ---- input projections + ReLU ----
    int ga = (Na + 63) / 64, gb = (Nb + 63) / 64;
    int gn[2] = {ga, gb};
    gemm_tile<1><<<ga, 256, 0, stream>>>(x_a, lin_W_a, lin_b_a, nullptr, nullptr, x[0], Na, 64);
    gemm_tile<1><<<gb, 256, 0, stream>>>(x_b, lin_W_b, lin_b_b, nullptr, nullptr, x[1], Nb, 32);

    const float scale = 0.25f;   // 1/sqrt(16)
    // relations: r0 aa(0->0), r1 ab(0->1), r2 ba(1->0), r3 bb(1->1)
    const int rs[4] = {0, 0, 1, 1};

    for (int l = 0; l < 2; ++l) {
        // ---- dt=1 tilde (rel ab=1 local0, bb=3 local1) ----
        for (int i = 0; i < 2; ++i) {
            int r = (i == 0) ? 1 : 3;
            int st = rs[r];
            gemm_dual<<<gn[st], 256, 0, stream>>>(x[st],
                Wt + (size_t)(l * 8 + r * 2 + 0) * HIDC * HIDC, bt + (size_t)(l * 8 + r * 2 + 0) * HIDC,
                Wt + (size_t)(l * 8 + r * 2 + 1) * HIDC * HIDC, bt + (size_t)(l * 8 + r * 2 + 1) * HIDC,
                kt[i], vt[i], Nn[st], HIDC);
        }
        // q for dt=1
        gemm_tile<0><<<gn[1], 256, 0, stream>>>(x[1], Wq + (size_t)(l * 2 + 1) * HIDC * HIDC,
                                                bq + (l * 2 + 1) * HIDC, nullptr, nullptr,
                                                qbuf, Nn[1], HIDC);
        // agg dt=1 -> msg
        agg_fused<<<(Nn[1] + 3) / 4, 256, 0, stream>>>(qbuf, kt[0], vt[0], kt[1], vt[1],
                                                       rowptr + (Nmax + 1), adj1,
                                                       prel + (l * 4 + 1) * NH, prel + (l * 4 + 3) * NH,
                                                       scale, msg, Nn[1]);
        // ---- dt=0 tilde (rel aa=0 local0, ba=2 local1) — overwrite kt/vt ----
        for (int i = 0; i < 2; ++i) {
            int r = (i == 0) ? 0 : 2;
            int st = rs[r];
            gemm_dual<<<gn[st], 256, 0, stream>>>(x[st],
                Wt + (size_t)(l * 8 + r * 2 + 0) * HIDC * HIDC, bt + (size_t)(l * 8 + r * 2 + 0) * HIDC,
                Wt + (size_t)(l * 8 + r * 2 + 1) * HIDC * HIDC, bt + (size_t)(l * 8 + r * 2 + 1) * HIDC,
                kt[i], vt[i], Nn[st], HIDC);
        }
        // q for dt=0 (qbuf free after agg dt=1)
        gemm_tile<0><<<gn[0], 256, 0, stream>>>(x[0], Wq + (size_t)(l * 2 + 0) * HIDC * HIDC,
                                                bq + (l * 2 + 0) * HIDC, nullptr, nullptr,
                                                qbuf, Nn[0], HIDC);
        // outproj dt=1 (all readers of x[1] are done) — in-place
        gemm_tile<2><<<gn[1], 256, 0, stream>>>(msg, Wa + (size_t)(l * 2 + 1) * HIDC * HIDC,
                                                ba + (l * 2 + 1) * HIDC, x[1],
                                                skip + (l * 2 + 1), x[1], Nn[1], HIDC);
        // agg dt=0 -> msg (msg free after outproj dt=1)
        agg_fused<<<(Nn[0] + 3) / 4, 256, 0, stream>>>(qbuf, kt[0], vt[0], kt[1], vt[1],
                                                       rowptr, adj0,
                                                       prel + (l * 4 + 0) * NH, prel + (l * 4 + 2) * NH,
                                                       scale, msg, Nn[0]);
        // outproj dt=0 — in-place
        gemm_tile<2><<<gn[0], 256, 0, stream>>>(msg, Wa + (size_t)(l * 2 + 0) * HIDC * HIDC,
                                                ba + (l * 2 + 0) * HIDC, x[0],
                                                skip + (l * 2 + 0), x[0], Nn[0], HIDC);
    }

    cls_kernel<<<Na, 128, 0, stream>>>(x[0], Wcls, bcls, (float*)d_out);
}

// Round 6
// 988.465 us; speedup vs baseline: 3.0290x; 1.1761x over previous
//
#include <hip/hip_runtime.h>
#include <math.h>

#define HIDC 128
#define NH 8
#define HD 16
#define NCLS 4

typedef __attribute__((ext_vector_type(8))) short s8v;
typedef __attribute__((ext_vector_type(4))) float f4v;

__device__ __forceinline__ float gelu_f(float h) {
    float z = 0.7978845608028654f * (h + 0.044715f * h * h * h);
    float t = 1.f - 2.f / (1.f + __expf(2.f * z));   // tanh(z)
    return 0.5f * h * (1.f + t);
}
__device__ __forceinline__ unsigned short f2bf(float x) {
    unsigned b = __float_as_uint(x);
    unsigned r = (b + 0x7FFFu + ((b >> 16) & 1u)) >> 16;
    return (unsigned short)r;
}
__device__ __forceinline__ float bf2f(unsigned short u) {
    return __uint_as_float(((unsigned)u) << 16);
}

__global__ void zero_u32(unsigned* __restrict__ p, long n)
{
    long i = (long)blockIdx.x * blockDim.x + threadIdx.x;
    long stride = (long)gridDim.x * blockDim.x;
    for (; i < n; i += stride) p[i] = 0u;
}

// Fold relation transforms into K/V projection weights (f32, [k][col]):
// bid = l*8 + r*2 + w (w: 0=K/arel, 1=V/mrel); src type st = r>>1.
__global__ void fold_all(const float* __restrict__ Wk, const float* __restrict__ bk,
                         const float* __restrict__ Wv, const float* __restrict__ bv,
                         const float* __restrict__ arel, const float* __restrict__ mrel,
                         float* __restrict__ Wt, float* __restrict__ bt)
{
    __shared__ float rsh[NH * HD * HD];
    int bid = blockIdx.x;
    int w = bid & 1, r = (bid >> 1) & 3, l = bid >> 3;
    int st = r >> 1;
    const float* W   = (w ? Wv : Wk) + (size_t)(l * 2 + st) * HIDC * HIDC;
    const float* bb  = (w ? bv : bk) + (size_t)(l * 2 + st) * HIDC;
    const float* rel = (w ? mrel : arel) + (size_t)(l * 4 + r) * NH * HD * HD;
    float* wt  = Wt + (size_t)bid * HIDC * HIDC;
    float* btp = bt + (size_t)bid * HIDC;

    int t = threadIdx.x;
    for (int i = t; i < NH * HD * HD; i += 128) rsh[i] = rel[i];
    __syncthreads();
    int h = t >> 4, f = t & 15;
    const float* rh = rsh + h * HD * HD + f;
    for (int k = 0; k < HIDC; ++k) {
        float acc = 0.f;
        const float* wr = W + (size_t)k * HIDC + h * HD;
        #pragma unroll
        for (int d = 0; d < HD; ++d) acc = fmaf(wr[d], rh[d * HD], acc);
        wt[(size_t)k * HIDC + t] = acc;
    }
    float accb = 0.f;
    const float* br = bb + h * HD;
    #pragma unroll
    for (int d = 0; d < HD; ++d) accb = fmaf(br[d], rh[d * HD], accb);
    btp[t] = accb;
}

// Transpose + split all GEMM weights to bf16 hi/lo, layout [col][k] (stride K).
// Weight order: wi0=lin_W_a(K=Ka), wi1=lin_W_b(K=Kb), then K=128: Wq x4, Wa x4, Wt x16.
__global__ __launch_bounds__(128)
void wsplit(const float* __restrict__ linWa, const float* __restrict__ linWb,
            const float* __restrict__ Wq, const float* __restrict__ Wa,
            const float* __restrict__ Wt,
            unsigned short* __restrict__ Whi, unsigned short* __restrict__ Wlo,
            int Ka, int Kb)
{
    int c = blockIdx.x;
    int nc0 = Ka >> 5, nc1 = Kb >> 5;
    const float* src; int K; size_t doff; int kc;
    if (c < nc0) { src = linWa; K = Ka; doff = 0; kc = c; }
    else if (c < nc0 + nc1) { src = linWb; K = Kb; doff = (size_t)HIDC * Ka; kc = c - nc0; }
    else {
        int cc = c - nc0 - nc1;
        int wi = cc >> 2; kc = cc & 3; K = 128;
        doff = (size_t)HIDC * (Ka + Kb) + (size_t)wi * 16384;
        if (wi < 4) src = Wq + (size_t)wi * 16384;
        else if (wi < 8) src = Wa + (size_t)(wi - 4) * 16384;
        else src = Wt + (size_t)(wi - 8) * 16384;
    }
    int t = threadIdx.x;   // col
    for (int k = kc * 32; k < kc * 32 + 32; ++k) {
        float x = src[(size_t)k * HIDC + t];
        unsigned short h = f2bf(x);
        Whi[doff + (size_t)t * K + k] = h;
        Wlo[doff + (size_t)t * K + k] = f2bf(x - bf2f(h));
    }
}

// ---- CSR build ----
__global__ void hist_kernel(const int* __restrict__ d1, int E1,
                            const int* __restrict__ d2, int E2,
                            unsigned* __restrict__ cnt)
{
    int i = blockIdx.x * blockDim.x + threadIdx.x;
    int tot = E1 + E2;
    int stride = gridDim.x * blockDim.x;
    for (; i < tot; i += stride) {
        int d = (i < E1) ? d1[i] : d2[i - E1];
        atomicAdd(&cnt[d], 1u);
    }
}

__global__ __launch_bounds__(256)
void scan_p1(const unsigned* __restrict__ cnt, unsigned* __restrict__ bsum,
             int Nmax, int nblk, int n0, int n1)
{
    int ty = blockIdx.x / nblk, b = blockIdx.x % nblk;
    int n = ty ? n1 : n0;
    const unsigned* c = cnt + (size_t)ty * Nmax;
    int i0 = b * 1024 + threadIdx.x * 4;
    unsigned s = 0;
    #pragma unroll
    for (int j = 0; j < 4; ++j) { int i = i0 + j; if (i < n) s += c[i]; }
    __shared__ unsigned sh[256];
    sh[threadIdx.x] = s; __syncthreads();
    for (int off = 128; off; off >>= 1) {
        if (threadIdx.x < (unsigned)off) sh[threadIdx.x] += sh[threadIdx.x + off];
        __syncthreads();
    }
    if (threadIdx.x == 0) bsum[blockIdx.x] = sh[0];
}

__global__ __launch_bounds__(256)
void scan_p2(unsigned* __restrict__ bsum, int nblk, int* __restrict__ rowptr,
             int Nmax, int n0, int n1)
{
    __shared__ unsigned sh[256];
    int tot = 2 * nblk;
    int t = threadIdx.x;
    unsigned v = (t < tot) ? bsum[t] : 0u;
    sh[t] = v; __syncthreads();
    for (int off = 1; off < 256; off <<= 1) {
        unsigned add = (t >= off) ? sh[t - off] : 0u;
        __syncthreads(); sh[t] += add; __syncthreads();
    }
    unsigned t0 = sh[nblk - 1];
    unsigned tall = sh[255];
    unsigned excl = sh[t] - v;
    if (t < tot) bsum[t] = (t < nblk) ? excl : excl - t0;
    if (t == 0) {
        rowptr[n0] = (int)t0;
        rowptr[(Nmax + 1) + n1] = (int)(tall - t0);
    }
}

__global__ __launch_bounds__(256)
void scan_p3(const unsigned* __restrict__ cnt, const unsigned* __restrict__ bsum,
             int* __restrict__ rowptr, unsigned* __restrict__ cursor,
             int Nmax, int nblk, int n0, int n1)
{
    int ty = blockIdx.x / nblk, b = blockIdx.x % nblk;
    int n = ty ? n1 : n0;
    const unsigned* c = cnt + (size_t)ty * Nmax;
    int* rp = rowptr + (size_t)ty * (Nmax + 1);
    unsigned* cur = cursor + (size_t)ty * Nmax;
    int t = threadIdx.x;
    int i0 = b * 1024 + t * 4;
    unsigned v[4]; unsigned s = 0;
    #pragma unroll
    for (int j = 0; j < 4; ++j) { int i = i0 + j; v[j] = (i < n) ? c[i] : 0u; s += v[j]; }
    __shared__ unsigned sh[256];
    sh[t] = s; __syncthreads();
    for (int off = 1; off < 256; off <<= 1) {
        unsigned add = (t >= off) ? sh[t - off] : 0u;
        __syncthreads(); sh[t] += add; __syncthreads();
    }
    unsigned run = bsum[blockIdx.x] + sh[t] - s;
    #pragma unroll
    for (int j = 0; j < 4; ++j) {
        int i = i0 + j;
        if (i < n) { rp[i] = (int)run; cur[i] = run; }
        run += v[j];
    }
}

__global__ void scatter_kernel(const int* __restrict__ s1, const int* __restrict__ d1, int E1,
                               const int* __restrict__ s2, const int* __restrict__ d2, int E2,
                               unsigned* __restrict__ cursor, unsigned* __restrict__ adj)
{
    int i = blockIdx.x * blockDim.x + threadIdx.x;
    int tot = E1 + E2;
    int stride = gridDim.x * blockDim.x;
    for (; i < tot; i += stride) {
        int s, d; unsigned rb;
        if (i < E1) { s = s1[i]; d = d1[i]; rb = 0u; }
        else        { s = s2[i - E1]; d = d2[i - E1]; rb = 1u << 24; }
        unsigned pos = atomicAdd(&cursor[d], 1u);
        adj[pos] = (unsigned)s | rb;
    }
}

// ---- MFMA GEMM: C[N x 128] = EPI(A[N x K] @ W + bias), split-bf16 3-product ----
// AMODE: 0 = plain A, 1 = A := gelu(A) on load (msg is already softmax-normalized)
// EPI:   0 = none, 1 = relu, 2 = blend with xold via sigmoid(skip)
// Weights pre-transposed+split: Bh/Bl layout [col][k], stride K.
// Block 256 thr (4 waves), tile 128 rows x 128 cols; wave w owns rows w*32..+31.
template <int AMODE, int EPI, int DUAL>
__global__ __launch_bounds__(256)
void mgemm(const float* __restrict__ A,
           const unsigned short* __restrict__ Bh1, const unsigned short* __restrict__ Bl1,
           const float* __restrict__ bias1,
           const unsigned short* __restrict__ Bh2, const unsigned short* __restrict__ Bl2,
           const float* __restrict__ bias2,
           const float* __restrict__ xold, const float* __restrict__ skipp,
           float* __restrict__ C1, float* __restrict__ C2, int N, int K)
{
    int t = threadIdx.x;
    int w = t >> 6, lane = t & 63;
    int lr = lane & 15, lk = (lane >> 4) * 8;
    int row0 = blockIdx.x * 128 + w * 32;

    f4v acc1[2][8], acc2[2][8];
    #pragma unroll
    for (int i = 0; i < 2; ++i)
        #pragma unroll
        for (int j = 0; j < 8; ++j) {
            acc1[i][j] = (f4v)0.f;
            if (DUAL) acc2[i][j] = (f4v)0.f;
        }

    for (int k0 = 0; k0 < K; k0 += 32) {
        s8v ah[2], al[2];
        #pragma unroll
        for (int fm = 0; fm < 2; ++fm) {
            int row = row0 + fm * 16 + lr;
            float xv[8];
            if (row < N) {
                const float* ap = A + (size_t)row * K + k0 + lk;
                float4 p = *(const float4*)ap;
                float4 q = *(const float4*)(ap + 4);
                xv[0] = p.x; xv[1] = p.y; xv[2] = p.z; xv[3] = p.w;
                xv[4] = q.x; xv[5] = q.y; xv[6] = q.z; xv[7] = q.w;
                if (AMODE == 1) {
                    #pragma unroll
                    for (int j = 0; j < 8; ++j) xv[j] = gelu_f(xv[j]);
                }
            } else {
                #pragma unroll
                for (int j = 0; j < 8; ++j) xv[j] = 0.f;
            }
            #pragma unroll
            for (int j = 0; j < 8; ++j) {
                unsigned short h = f2bf(xv[j]);
                ah[fm][j] = (short)h;
                al[fm][j] = (short)f2bf(xv[j] - bf2f(h));
            }
        }
        #pragma unroll
        for (int fn = 0; fn < 8; ++fn) {
            size_t boff = (size_t)(fn * 16 + lr) * K + k0 + lk;
            s8v bh = *(const s8v*)(Bh1 + boff);
            s8v bl = *(const s8v*)(Bl1 + boff);
            #pragma unroll
            for (int fm = 0; fm < 2; ++fm) {
                acc1[fm][fn] = __builtin_amdgcn_mfma_f32_16x16x32_bf16(ah[fm], bh, acc1[fm][fn], 0, 0, 0);
                acc1[fm][fn] = __builtin_amdgcn_mfma_f32_16x16x32_bf16(ah[fm], bl, acc1[fm][fn], 0, 0, 0);
                acc1[fm][fn] = __builtin_amdgcn_mfma_f32_16x16x32_bf16(al[fm], bh, acc1[fm][fn], 0, 0, 0);
            }
            if (DUAL) {
                s8v bh2 = *(const s8v*)(Bh2 + boff);
                s8v bl2 = *(const s8v*)(Bl2 + boff);
                #pragma unroll
                for (int fm = 0; fm < 2; ++fm) {
                    acc2[fm][fn] = __builtin_amdgcn_mfma_f32_16x16x32_bf16(ah[fm], bh2, acc2[fm][fn], 0, 0, 0);
                    acc2[fm][fn] = __builtin_amdgcn_mfma_f32_16x16x32_bf16(ah[fm], bl2, acc2[fm][fn], 0, 0, 0);
                    acc2[fm][fn] = __builtin_amdgcn_mfma_f32_16x16x32_bf16(al[fm], bh2, acc2[fm][fn], 0, 0, 0);
                }
            }
        }
    }

    float bv1[8], bv2[8];
    #pragma unroll
    for (int fn = 0; fn < 8; ++fn) {
        bv1[fn] = bias1[fn * 16 + lr];
        if (DUAL) bv2[fn] = bias2[fn * 16 + lr];
    }
    float beta = 0.f;
    if (EPI == 2) beta = 1.f / (1.f + __expf(-skipp[0]));
    int rbase = (lane >> 4) * 4;
    #pragma unroll
    for (int fm = 0; fm < 2; ++fm) {
        #pragma unroll
        for (int j = 0; j < 4; ++j) {
            int row = row0 + fm * 16 + rbase + j;
            if (row >= N) continue;
            #pragma unroll
            for (int fn = 0; fn < 8; ++fn) {
                int col = fn * 16 + lr;
                float o = acc1[fm][fn][j] + bv1[fn];
                if (EPI == 1) o = fmaxf(o, 0.f);
                if (EPI == 2) {
                    float xo = xold[(size_t)row * HIDC + col];
                    o = beta * o + (1.f - beta) * xo;
                }
                C1[(size_t)row * HIDC + col] = o;
                if (DUAL) C2[(size_t)row * HIDC + col] = acc2[fm][fn][j] + bv2[fn];
            }
        }
    }
}

// ---- fused per-destination online-softmax aggregation (writes normalized avg) ----
__global__ __launch_bounds__(256)
void agg_fused(const float* __restrict__ Q,
               const float* __restrict__ ktA, const float* __restrict__ vtA,
               const float* __restrict__ ktB, const float* __restrict__ vtB,
               const int* __restrict__ rowptr, const unsigned* __restrict__ adj,
               const float* __restrict__ prelA, const float* __restrict__ prelB,
               float scale, float* __restrict__ msg, int N)
{
    int node = blockIdx.x * 4 + (threadIdx.x >> 6);
    if (node >= N) return;
    int lane = threadIdx.x & 63;
    int h = lane >> 3;
    float spA = prelA[h] * scale, spB = prelB[h] * scale;
    float2 qv = *(const float2*)(Q + (size_t)node * HIDC + lane * 2);
    int beg = rowptr[node], end = rowptr[node + 1];
    float m = -INFINITY, s = 0.f;
    float accx = 0.f, accy = 0.f;
    for (int i = beg; i < end; ++i) {
        unsigned ent = adj[i];
        int src = (int)(ent & 0xFFFFFFu);
        int rl = (int)(ent >> 24);
        const float* kt = rl ? ktB : ktA;
        const float* vt = rl ? vtB : vtA;
        float2 kv = *(const float2*)(kt + (size_t)src * HIDC + lane * 2);
        float2 vv = *(const float2*)(vt + (size_t)src * HIDC + lane * 2);
        float p = kv.x * qv.x + kv.y * qv.y;
        p += __shfl_xor(p, 1, 8);
        p += __shfl_xor(p, 2, 8);
        p += __shfl_xor(p, 4, 8);
        float a = p * (rl ? spB : spA);
        float mn = fmaxf(m, a);
        float c = __expf(m - mn);
        float pe = __expf(a - mn);
        s = s * c + pe;
        accx = accx * c + pe * vv.x;
        accy = accy * c + pe * vv.y;
        m = mn;
    }
    float inv = 1.f / fmaxf(s, 1e-16f);
    float2 o;
    o.x = accx * inv;
    o.y = accy * inv;
    *(float2*)(msg + (size_t)node * HIDC + lane * 2) = o;
}

// out[row, c] = x[row]·Wcls[c] + bcls[c]
__global__ __launch_bounds__(128)
void cls_kernel(const float* __restrict__ X, const float* __restrict__ Wc,
                const float* __restrict__ bc, float* __restrict__ out)
{
    int row = blockIdx.x, t = threadIdx.x;
    int c = t >> 5, j = t & 31;
    const float* xr = X + (size_t)row * HIDC;
    const float* w = Wc + c * HIDC;
    float p = 0.f;
    for (int k = j; k < HIDC; k += 32) p = fmaf(xr[k], w[k], p);
    #pragma unroll
    for (int off = 16; off; off >>= 1) p += __shfl_xor(p, off, 32);
    if (j == 0) out[(size_t)row * NCLS + c] = p + bc[c];
}

extern "C" void kernel_launch(void* const* d_in, const int* in_sizes, int n_in,
                              void* d_out, int out_size, void* d_ws, size_t ws_size,
                              hipStream_t stream)
{
    const float* x_a    = (const float*)d_in[0];
    const float* x_b    = (const float*)d_in[1];
    const float* lin_W_a= (const float*)d_in[2];
    const float* lin_b_a= (const float*)d_in[3];
    const float* lin_W_b= (const float*)d_in[4];
    const float* lin_b_b= (const float*)d_in[5];
    const float* Wk     = (const float*)d_in[6];
    const float* bk     = (const float*)d_in[7];
    const float* Wq     = (const float*)d_in[8];
    const float* bq     = (const float*)d_in[9];
    const float* Wv     = (const float*)d_in[10];
    const float* bv     = (const float*)d_in[11];
    const float* arel   = (const float*)d_in[12];
    const float* mrel   = (const float*)d_in[13];
    const float* prel   = (const float*)d_in[14];
    const float* Wa     = (const float*)d_in[15];
    const float* ba     = (const float*)d_in[16];
    const float* skip   = (const float*)d_in[17];
    const float* Wcls   = (const float*)d_in[18];
    const float* bcls   = (const float*)d_in[19];
    const int* eptr[4] = {(const int*)d_in[20], (const int*)d_in[21],
                          (const int*)d_in[22], (const int*)d_in[23]};
    int Ee[4] = {in_sizes[20] / 2, in_sizes[21] / 2, in_sizes[22] / 2, in_sizes[23] / 2};

    int Ka = in_sizes[2] / HIDC;     // 64
    int Kb = in_sizes[4] / HIDC;     // 32
    int Na = in_sizes[0] / Ka;
    int Nb = in_sizes[1] / Kb;
    int Nn[2] = {Na, Nb};
    int Nmax = Na > Nb ? Na : Nb;

    // ---- workspace layout (all chunks multiples of 16B) ----
    char* base = (char*)d_ws;
    float* x[2];
    x[0] = (float*)base; base += (size_t)Na * HIDC * 4;
    x[1] = (float*)base; base += (size_t)Nb * HIDC * 4;
    float* qbuf = (float*)base; base += (size_t)Nmax * HIDC * 4;
    float* kt[2]; float* vt[2];
    for (int i = 0; i < 2; ++i) {
        kt[i] = (float*)base; base += (size_t)Nmax * HIDC * 4;
        vt[i] = (float*)base; base += (size_t)Nmax * HIDC * 4;
    }
    float* msg = (float*)base; base += (size_t)Nmax * HIDC * 4;
    float* Wt = (float*)base; base += (size_t)16 * HIDC * HIDC * 4;
    float* bt = (float*)base; base += (size_t)16 * HIDC * 4;
    size_t nWsplit = (size_t)HIDC * (Ka + Kb) + (size_t)24 * HIDC * HIDC; // ushorts
    unsigned short* Whi = (unsigned short*)base; base += nWsplit * 2;
    unsigned short* Wlo = (unsigned short*)base; base += nWsplit * 2;
    unsigned* cnt = (unsigned*)base; base += (size_t)2 * Nmax * 4;
    unsigned* cursor = (unsigned*)base; base += (size_t)2 * Nmax * 4;
    unsigned* bsum = (unsigned*)base; base += 256 * 4;
    int* rowptr = (int*)base; base += (size_t)2 * (Nmax + 1) * 4;
    unsigned* adj0 = (unsigned*)base; base += (size_t)(Ee[0] + Ee[2]) * 4;
    unsigned* adj1 = (unsigned*)base; base += (size_t)(Ee[1] + Ee[3]) * 4;

    // split-weight offsets (in ushorts)
    size_t off_lina = 0;
    size_t off_linb = (size_t)HIDC * Ka;
    size_t base128  = (size_t)HIDC * (Ka + Kb);
    auto offQ = [&](int l, int tt) { return base128 + (size_t)(l * 2 + tt) * 16384; };
    auto offA = [&](int l, int tt) { return base128 + (size_t)(4 + l * 2 + tt) * 16384; };
    auto offT = [&](int l, int r, int w) { return base128 + (size_t)(8 + l * 8 + r * 2 + w) * 16384; };

    // ---- fold + weight split (once per launch) ----
    fold_all<<<16, 128, 0, stream>>>(Wk, bk, Wv, bv, arel, mrel, Wt, bt);
    int nchunks = (Ka >> 5) + (Kb >> 5) + 24 * 4;
    wsplit<<<nchunks, 128, 0, stream>>>(lin_W_a, lin_W_b, Wq, Wa, Wt, Whi, Wlo, Ka, Kb);

    // ---- CSR build ----
    int nblk = (Nmax + 1023) / 1024;
    zero_u32<<<512, 256, 0, stream>>>(cnt, (long)2 * Nmax);
    hist_kernel<<<1024, 256, 0, stream>>>(eptr[0] + Ee[0], Ee[0], eptr[2] + Ee[2], Ee[2], cnt);
    hist_kernel<<<1024, 256, 0, stream>>>(eptr[1] + Ee[1], Ee[1], eptr[3] + Ee[3], Ee[3], cnt + Nmax);
    scan_p1<<<2 * nblk, 256, 0, stream>>>(cnt, bsum, Nmax, nblk, Na, Nb);
    scan_p2<<<1, 256, 0, stream>>>(bsum, nblk, rowptr, Nmax, Na, Nb);
    scan_p3<<<2 * nblk, 256, 0, stream>>>(cnt, bsum, rowptr, cursor, Nmax, nblk, Na, Nb);
    scatter_kernel<<<1024, 256, 0, stream>>>(eptr[0], eptr[0] + Ee[0], Ee[0],
                                             eptr[2], eptr[2] + Ee[2], Ee[2], cursor, adj0);
    scatter_kernel<<<1024, 256, 0, stream>>>(eptr[1], eptr[1] + Ee[1], Ee[1],
                                             eptr[3], eptr[3] + Ee[3], Ee[3], cursor + Nmax, adj1);

    // ---- input projections + ReLU ----
    int gn[2] = {(Na + 127) / 128, (Nb + 127) / 128};
    mgemm<0, 1, 0><<<gn[0], 256, 0, stream>>>(x_a, Whi + off_lina, Wlo + off_lina,
                                              lin_b_a, nullptr, nullptr, nullptr,
                                              nullptr, nullptr, x[0], nullptr, Na, Ka);
    mgemm<0, 1, 0><<<gn[1], 256, 0, stream>>>(x_b, Whi + off_linb, Wlo + off_linb,
                                              lin_b_b, nullptr, nullptr, nullptr,
                                              nullptr, nullptr, x[1], nullptr, Nb, Kb);

    const float scale = 0.25f;   // 1/sqrt(16)
    const int rs[4] = {0, 0, 1, 1};   // r0 aa, r1 ab, r2 ba, r3 bb

    for (int l = 0; l < 2; ++l) {
        // dt=1 tilde: rel ab=1 (slot 0), bb=3 (slot 1)
        for (int i = 0; i < 2; ++i) {
            int r = (i == 0) ? 1 : 3;
            int st = rs[r];
            mgemm<0, 0, 1><<<gn[st], 256, 0, stream>>>(x[st],
                Whi + offT(l, r, 0), Wlo + offT(l, r, 0), bt + (size_t)(l * 8 + r * 2 + 0) * HIDC,
                Whi + offT(l, r, 1), Wlo + offT(l, r, 1), bt + (size_t)(l * 8 + r * 2 + 1) * HIDC,
                nullptr, nullptr, kt[i], vt[i], Nn[st], HIDC);
        }
        mgemm<0, 0, 0><<<gn[1], 256, 0, stream>>>(x[1],
            Whi + offQ(l, 1), Wlo + offQ(l, 1), bq + (l * 2 + 1) * HIDC,
            nullptr, nullptr, nullptr, nullptr, nullptr, qbuf, nullptr, Nn[1], HIDC);
        agg_fused<<<(Nn[1] + 3) / 4, 256, 0, stream>>>(qbuf, kt[0], vt[0], kt[1], vt[1],
                                                       rowptr + (Nmax + 1), adj1,
                                                       prel + (l * 4 + 1) * NH, prel + (l * 4 + 3) * NH,
                                                       scale, msg, Nn[1]);
        // dt=0 tilde: rel aa=0 (slot 0), ba=2 (slot 1)
        for (int i = 0; i < 2; ++i) {
            int r = (i == 0) ? 0 : 2;
            int st = rs[r];
            mgemm<0, 0, 1><<<gn[st], 256, 0, stream>>>(x[st],
                Whi + offT(l, r, 0), Wlo + offT(l, r, 0), bt + (size_t)(l * 8 + r * 2 + 0) * HIDC,
                Whi + offT(l, r, 1), Wlo + offT(l, r, 1), bt + (size_t)(l * 8 + r * 2 + 1) * HIDC,
                nullptr, nullptr, kt[i], vt[i], Nn[st], HIDC);
        }
        mgemm<0, 0, 0><<<gn[0], 256, 0, stream>>>(x[0],
            Whi + offQ(l, 0), Wlo + offQ(l, 0), bq + (l * 2 + 0) * HIDC,
            nullptr, nullptr, nullptr, nullptr, nullptr, qbuf, nullptr, Nn[0], HIDC);
        // outproj dt=1 (x[1] no longer read this layer) — in place
        mgemm<1, 2, 0><<<gn[1], 256, 0, stream>>>(msg,
            Whi + offA(l, 1), Wlo + offA(l, 1), ba + (l * 2 + 1) * HIDC,
            nullptr, nullptr, nullptr, x[1], skip + (l * 2 + 1), x[1], nullptr, Nn[1], HIDC);
        agg_fused<<<(Nn[0] + 3) / 4, 256, 0, stream>>>(qbuf, kt[0], vt[0], kt[1], vt[1],
                                                       rowptr, adj0,
                                                       prel + (l * 4 + 0) * NH, prel + (l * 4 + 2) * NH,
                                                       scale, msg, Nn[0]);
        mgemm<1, 2, 0><<<gn[0], 256, 0, stream>>>(msg,
            Whi + offA(l, 0), Wlo + offA(l, 0), ba + (l * 2 + 0) * HIDC,
            nullptr, nullptr, nullptr, x[0], skip + (l * 2 + 0), x[0], nullptr, Nn[0], HIDC);
    }

    cls_kernel<<<Na, 128, 0, stream>>>(x[0], Wcls, bcls, (float*)d_out);
}